// Round 1
// baseline (1436.764 us; speedup 1.0000x reference)
//
#include <hip/hip_runtime.h>

#define NS   16384
#define NF1c 2000
#define NF2c 10000
#define NH   512
#define KC   19
#define NREC 12000

typedef short bf16x8 __attribute__((ext_vector_type(8)));
typedef float f32x4  __attribute__((ext_vector_type(4)));

__device__ __forceinline__ unsigned short f2bf(float x) {
    unsigned int u = __builtin_bit_cast(unsigned int, x);
    u += 0x7FFFu + ((u >> 16) & 1u);          // round-to-nearest-even
    return (unsigned short)(u >> 16);
}
__device__ __forceinline__ float bf2f(unsigned short h) {
    return __builtin_bit_cast(float, (unsigned int)h << 16);
}

// ---------------- prep kernels ----------------
__global__ void k_cvt(const float* __restrict__ s, unsigned short* __restrict__ d, int n4) {
    int i = blockIdx.x * blockDim.x + threadIdx.x;
    int st = gridDim.x * blockDim.x;
    for (; i < n4; i += st) {
        float4 f = ((const float4*)s)[i];
        ushort4 o;
        o.x = f2bf(f.x); o.y = f2bf(f.y); o.z = f2bf(f.z); o.w = f2bf(f.w);
        ((ushort4*)d)[i] = o;
    }
}

__global__ void k_prep_st(const float* __restrict__ g, const float* __restrict__ be,
                          const float* __restrict__ m, const float* __restrict__ v,
                          const float* __restrict__ b1,
                          float* __restrict__ s, float* __restrict__ t, int n) {
    int i = blockIdx.x * blockDim.x + threadIdx.x;
    if (i < n) {
        float sc = g[i] * rsqrtf(v[i] + 1e-5f);
        s[i] = sc;
        t[i] = be[i] + (b1[i] - m[i]) * sc;
    }
}

__global__ void k_zero(float* __restrict__ p, int n) {
    int i = blockIdx.x * blockDim.x + threadIdx.x;
    if (i < n) p[i] = 0.f;
}

// ---------------- GEMM: C[M,Nn] = A[M,K] * B[Nn,K]^T  (both row-major, K fast) ----------
// EPI 0: h = bf16(relu(acc*sc[col]+sh[col])) -> Hout (ld = NH)
// EPI 1: Fout[row*Nn+col] = acc + sc[col]  (col guarded)
// A_BF16 0: A is fp32 (convert in staging); 1: A is bf16
template<int EPI, int A_BF16>
__global__ __launch_bounds__(256)
void k_gemm(const void* __restrict__ Aptr, const unsigned short* __restrict__ B,
            int K, int Nn,
            const float* __restrict__ sc, const float* __restrict__ sh,
            unsigned short* __restrict__ Hout, float* __restrict__ Fout)
{
    __shared__ __align__(16) unsigned short As[128 * 32];
    __shared__ __align__(16) unsigned short Bs[128 * 32];
    const int tid  = threadIdx.x;
    const int tn   = blockIdx.x, tm = blockIdx.y;
    const int wave = tid >> 6, lane = tid & 63;
    const int wr   = wave >> 1, wc = wave & 1;
    const int lo   = lane & 15, hi = lane >> 4;
    const int srow = tid >> 1, shalf = tid & 1;
    const long arow = (long)tm * 128 + srow;
    const int  brow = tn * 128 + srow;

    f32x4 acc[4][4];
#pragma unroll
    for (int i = 0; i < 4; i++)
#pragma unroll
        for (int j = 0; j < 4; j++) acc[i][j] = (f32x4){0.f, 0.f, 0.f, 0.f};

    char* Ab = (char*)As;
    char* Bb = (char*)Bs;
    // swizzled chunk byte offset inside a [128 rows][4 chunks of 16B] tile
    const int wc0 = (srow << 6) + ((((shalf * 2)    ) ^ ((srow >> 1) & 3)) << 4);
    const int wc1 = (srow << 6) + ((((shalf * 2) + 1) ^ ((srow >> 1) & 3)) << 4);

    for (int k0 = 0; k0 < K; k0 += 32) {
        __syncthreads();
        const int kb = k0 + shalf * 16;
        // ---- stage A (convert fp32->bf16 if needed)
        {
            __align__(16) unsigned short u[16];
            if (A_BF16) {
                const unsigned short* ap = (const unsigned short*)Aptr + arow * (long)K + kb;
                *(uint4*)&u[0] = *(const uint4*)(ap);
                *(uint4*)&u[8] = *(const uint4*)(ap + 8);
            } else {
                const float* ap = (const float*)Aptr + arow * (long)K + kb;
                if (kb + 16 <= K) {
#pragma unroll
                    for (int q = 0; q < 4; q++) {
                        float4 f = ((const float4*)ap)[q];
                        u[q*4+0] = f2bf(f.x); u[q*4+1] = f2bf(f.y);
                        u[q*4+2] = f2bf(f.z); u[q*4+3] = f2bf(f.w);
                    }
                } else {
#pragma unroll
                    for (int j = 0; j < 16; j++)
                        u[j] = (kb + j < K) ? f2bf(ap[j]) : (unsigned short)0;
                }
            }
            *(uint4*)(Ab + wc0) = *(uint4*)&u[0];
            *(uint4*)(Ab + wc1) = *(uint4*)&u[8];
        }
        // ---- stage B (already bf16)
        {
            uint4 q0 = {0, 0, 0, 0}, q1 = {0, 0, 0, 0};
            if (brow < Nn && kb < K) {
                const unsigned short* bp = B + (long)brow * K + kb;
                if (kb + 16 <= K) {
                    q0 = *(const uint4*)bp;
                    q1 = *(const uint4*)(bp + 8);
                } else {
                    __align__(16) unsigned short tb[16];
#pragma unroll
                    for (int j = 0; j < 16; j++)
                        tb[j] = (kb + j < K) ? bp[j] : (unsigned short)0;
                    q0 = *(uint4*)&tb[0]; q1 = *(uint4*)&tb[8];
                }
            }
            *(uint4*)(Bb + wc0) = q0;
            *(uint4*)(Bb + wc1) = q1;
        }
        __syncthreads();
        // ---- fragments + MFMA
        bf16x8 af[4], bfr[4];
#pragma unroll
        for (int f = 0; f < 4; f++) {
            int ar = wr * 64 + f * 16 + lo;
            af[f]  = *(const bf16x8*)(Ab + (ar << 6) + ((hi ^ ((ar >> 1) & 3)) << 4));
            int br = wc * 64 + f * 16 + lo;
            bfr[f] = *(const bf16x8*)(Bb + (br << 6) + ((hi ^ ((br >> 1) & 3)) << 4));
        }
#pragma unroll
        for (int i = 0; i < 4; i++)
#pragma unroll
            for (int j = 0; j < 4; j++)
                acc[i][j] = __builtin_amdgcn_mfma_f32_16x16x32_bf16(af[i], bfr[j], acc[i][j], 0, 0, 0);
    }
    // ---- epilogue  (C/D layout: col = lane&15, row = (lane>>4)*4 + reg)
#pragma unroll
    for (int i = 0; i < 4; i++) {
#pragma unroll
        for (int j = 0; j < 4; j++) {
            const int col = tn * 128 + wc * 64 + j * 16 + lo;
#pragma unroll
            for (int r = 0; r < 4; r++) {
                const long row = (long)tm * 128 + wr * 64 + i * 16 + hi * 4 + r;
                float v = acc[i][j][r];
                if (EPI == 0) {
                    v = fmaxf(v * sc[col] + sh[col], 0.f);
                    Hout[row * NH + col] = f2bf(v);
                } else {
                    if (col < Nn) Fout[row * (long)Nn + col] = v + sc[col];
                }
            }
        }
    }
}

// ---------------- stage C: projections + scatter ----------------
__global__ __launch_bounds__(256)
void k_proj(const unsigned short* __restrict__ h_rna,
            const unsigned short* __restrict__ h_atac,
            const float* __restrict__ W_rmu, const float* __restrict__ b_rmu,
            const float* __restrict__ W_rvar, const float* __restrict__ b_rvar,
            const float* __restrict__ W_amu, const float* __restrict__ b_amu,
            const float* __restrict__ W_avar, const float* __restrict__ b_avar,
            const int* __restrict__ idx_rna, const int* __restrict__ idx_atac,
            float* __restrict__ mu0, float* __restrict__ var0,
            float* __restrict__ mu1, float* __restrict__ var1,
            float* __restrict__ mflag)
{
    __shared__ __align__(16) unsigned short hsh[4][2][NH];
    const int wave = threadIdx.x >> 6, lane = threadIdx.x & 63;
    const long i = (long)blockIdx.x * 4 + wave;
    *(uint4*)&hsh[wave][0][lane * 8] = *(const uint4*)(h_rna  + i * NH + lane * 8);
    *(uint4*)&hsh[wave][1][lane * 8] = *(const uint4*)(h_atac + i * NH + lane * 8);
    __syncthreads();
    const int mod = lane >> 5, oo = lane & 31;
    const int isv = oo >> 4, o = oo & 15;
    const float *W, *bias;
    if (mod == 0) { W = isv ? W_rvar : W_rmu; bias = isv ? b_rvar : b_rmu; }
    else          { W = isv ? W_avar : W_amu; bias = isv ? b_avar : b_amu; }
    const unsigned short* hr = hsh[wave][mod];
    const float* wrow = W + o * NH;
    float a = 0.f;
#pragma unroll 4
    for (int k = 0; k < NH; k += 4) {
        float4 w = *(const float4*)(wrow + k);
        a += bf2f(hr[k]) * w.x + bf2f(hr[k+1]) * w.y + bf2f(hr[k+2]) * w.z + bf2f(hr[k+3]) * w.w;
    }
    a += bias[o];
    const int tgt = (mod == 0) ? idx_rna[i] : idx_atac[i];
    float* mu  = mod ? mu1  : mu0;
    float* var = mod ? var1 : var0;
    if (!isv) mu[(long)tgt * 16 + o] = a;
    else      var[(long)tgt * 16 + o] = expf(a);
    if (oo == 0) mflag[(long)mod * NS + tgt] = 1.f;
}

// ---------------- stage C: PoE combine + q + decoder hidden ----------------
__global__ __launch_bounds__(256)
void k_combine(const float* __restrict__ mu0, const float* __restrict__ var0,
               const float* __restrict__ mu1, const float* __restrict__ var1,
               const float* __restrict__ mflag,
               const float* __restrict__ eps, const float* __restrict__ cluster,
               const float* __restrict__ W_d1,
               const float* __restrict__ s_d, const float* __restrict__ t_d,
               float* __restrict__ o_zmu, float* __restrict__ o_zvar,
               float* __restrict__ o_z, float* __restrict__ o_q,
               unsigned short* __restrict__ h_d)
{
    __shared__ float zsh[4][16];
    const int wave = threadIdx.x >> 6, lane = threadIdx.x & 63;
    const long i = (long)blockIdx.x * 4 + wave;
    if (lane < 16) {
        const int d = lane;
        const float f0 = mflag[i], f1 = mflag[NS + i];
        float ts = 1.f, num = 0.f;
        if (f0 != 0.f) { float iv = 1.f / var0[i*16+d]; ts += iv; num += mu0[i*16+d] * iv; }
        if (f1 != 0.f) { float iv = 1.f / var1[i*16+d]; ts += iv; num += mu1[i*16+d] * iv; }
        const float zm = num / ts, zv = 1.f / ts;
        const float z = zm + zv * eps[i*16+d];
        o_zmu[i*16+d] = zm; o_zvar[i*16+d] = zv; o_z[i*16+d] = z;
        zsh[wave][d] = z;
    }
    __syncthreads();
    float zreg[16];
#pragma unroll
    for (int d = 0; d < 16; d++) zreg[d] = zsh[wave][d];
    float qk = 0.f;
    if (lane < KC) {
        float d2 = 0.f;
#pragma unroll
        for (int d = 0; d < 16; d++) { float df = zreg[d] - cluster[lane*16+d]; d2 += df*df; }
        qk = 1.f / (1.f + d2);
    }
    float ssum = qk;
#pragma unroll
    for (int off = 16; off > 0; off >>= 1) ssum += __shfl_xor(ssum, off, 32);
    if (lane < KC) o_q[i * KC + lane] = qk / ssum;
#pragma unroll
    for (int j = 0; j < 8; j++) {
        const int c = lane + 64 * j;
        float a = 0.f;
#pragma unroll
        for (int d = 0; d < 16; d += 4) {
            float4 w = *(const float4*)(W_d1 + c * 16 + d);
            a += zreg[d] * w.x + zreg[d+1] * w.y + zreg[d+2] * w.z + zreg[d+3] * w.w;
        }
        a = fmaxf(a * s_d[c] + t_d[c], 0.f);
        h_d[i * NH + c] = f2bf(a);
    }
}

// ---------------- launcher ----------------
extern "C" void kernel_launch(void* const* d_in, const int* in_sizes, int n_in,
                              void* d_out, int out_size, void* d_ws, size_t ws_size,
                              hipStream_t stream)
{
    const float* rna    = (const float*)d_in[0];
    const float* atac   = (const float*)d_in[1];
    const int*   i_rna  = (const int*)d_in[2];
    const int*   i_atac = (const int*)d_in[3];
    const float* eps    = (const float*)d_in[4];
    const float* W_r1   = (const float*)d_in[5];
    const float* b_r1   = (const float*)d_in[6];
    const float* g_r    = (const float*)d_in[7];
    const float* be_r   = (const float*)d_in[8];
    const float* m_r    = (const float*)d_in[9];
    const float* v_r    = (const float*)d_in[10];
    const float* W_rmu  = (const float*)d_in[11];
    const float* b_rmu  = (const float*)d_in[12];
    const float* W_rvar = (const float*)d_in[13];
    const float* b_rvar = (const float*)d_in[14];
    const float* W_a1   = (const float*)d_in[15];
    const float* b_a1   = (const float*)d_in[16];
    const float* g_a    = (const float*)d_in[17];
    const float* be_a   = (const float*)d_in[18];
    const float* m_a    = (const float*)d_in[19];
    const float* v_a    = (const float*)d_in[20];
    const float* W_amu  = (const float*)d_in[21];
    const float* b_amu  = (const float*)d_in[22];
    const float* W_avar = (const float*)d_in[23];
    const float* b_avar = (const float*)d_in[24];
    const float* W_d1   = (const float*)d_in[25];
    const float* b_d1   = (const float*)d_in[26];
    const float* g_d    = (const float*)d_in[27];
    const float* be_d   = (const float*)d_in[28];
    const float* m_d    = (const float*)d_in[29];
    const float* v_d    = (const float*)d_in[30];
    const float* W_d4   = (const float*)d_in[31];
    const float* b_d4   = (const float*)d_in[32];
    const float* clus   = (const float*)d_in[33];
    (void)in_sizes; (void)n_in; (void)out_size;

    char* w = (char*)d_ws;
    size_t off = 0;
    auto carve = [&](size_t bytes) { void* p = w + off; off += (bytes + 255) & ~(size_t)255; return p; };
    unsigned short* wr1b  = (unsigned short*)carve((size_t)NH * NF1c * 2);
    unsigned short* wa1b  = (unsigned short*)carve((size_t)NH * NF2c * 2);
    unsigned short* wd4b  = (unsigned short*)carve((size_t)NREC * NH * 2);
    unsigned short* hrna  = (unsigned short*)carve((size_t)NS * NH * 2);
    unsigned short* hatac = (unsigned short*)carve((size_t)NS * NH * 2);
    unsigned short* hd    = (unsigned short*)carve((size_t)NS * NH * 2);
    float* mu0   = (float*)carve((size_t)NS * 16 * 4);
    float* var0  = (float*)carve((size_t)NS * 16 * 4);
    float* mu1   = (float*)carve((size_t)NS * 16 * 4);
    float* var1  = (float*)carve((size_t)NS * 16 * 4);
    float* mflag = (float*)carve((size_t)2 * NS * 4);
    float* st    = (float*)carve((size_t)6 * NH * 4);
    if (off > ws_size) return;  // insufficient workspace -> loud validation failure

    float* s_r = st;          float* t_r = st + NH;
    float* s_a = st + 2*NH;   float* t_a = st + 3*NH;
    float* s_d = st + 4*NH;   float* t_d = st + 5*NH;

    float* out    = (float*)d_out;
    float* o_rec  = out;
    float* o_zmu  = out + (size_t)NS * NREC;
    float* o_zvar = o_zmu + (size_t)NS * 16;
    float* o_z    = o_zvar + (size_t)NS * 16;
    float* o_q    = o_z + (size_t)NS * 16;

    // prep
    k_cvt<<<1024, 256, 0, stream>>>(W_r1, wr1b, NH * NF1c / 4);
    k_cvt<<<2048, 256, 0, stream>>>(W_a1, wa1b, NH * NF2c / 4);
    k_cvt<<<2048, 256, 0, stream>>>(W_d4, wd4b, NREC * NH / 4);
    k_prep_st<<<2, 256, 0, stream>>>(g_r, be_r, m_r, v_r, b_r1, s_r, t_r, NH);
    k_prep_st<<<2, 256, 0, stream>>>(g_a, be_a, m_a, v_a, b_a1, s_a, t_a, NH);
    k_prep_st<<<2, 256, 0, stream>>>(g_d, be_d, m_d, v_d, b_d1, s_d, t_d, NH);
    k_zero<<<(2 * NS + 255) / 256, 256, 0, stream>>>(mflag, 2 * NS);

    dim3 blk(256);
    dim3 ge(4, 128);
    k_gemm<0, 0><<<ge, blk, 0, stream>>>(rna,  wr1b, NF1c, NH, s_r, t_r, hrna,  nullptr);
    k_gemm<0, 0><<<ge, blk, 0, stream>>>(atac, wa1b, NF2c, NH, s_a, t_a, hatac, nullptr);
    k_proj<<<NS / 4, blk, 0, stream>>>(hrna, hatac, W_rmu, b_rmu, W_rvar, b_rvar,
                                       W_amu, b_amu, W_avar, b_avar, i_rna, i_atac,
                                       mu0, var0, mu1, var1, mflag);
    k_combine<<<NS / 4, blk, 0, stream>>>(mu0, var0, mu1, var1, mflag, eps, clus,
                                          W_d1, s_d, t_d, o_zmu, o_zvar, o_z, o_q, hd);
    dim3 gd(94, 128);
    k_gemm<1, 1><<<gd, blk, 0, stream>>>(hd, wd4b, NH, NREC, b_d4, nullptr, nullptr, o_rec);
}